// Round 14
// baseline (36.646 us; speedup 1.0000x reference)
//
#include <hip/hip_runtime.h>

// IIR filter bank: B=16, T=32768, F=30, order 6 (K=7).
// Overlap-and-discard chunking (lane chunk 64, WARM=128; trunc ~1.4e-3 *
// state ~ well under threshold; absmax flat 2.0 = FP-order noise).
// R13 "union" kernel — every individually-proven fix, none of the
// individually-falsified patterns:
//   - block=(b,f,4096-span), ONE wave; lane c -> chunk [64c,+64)  [R10]
//   - x staged via coalesced float4 global loads                  [R11]
//   - LDS 68-float group stride: all b128 ops start at bank
//     4(c+k) mod 32 -> balanced 8 lanes/bank-quad = conflict-free [new]
//   - lane window register-staged: 48 float4, then 192 pure-FMA
//     steps with zero memory stalls                               [R12]
//   - output overwrites group c+2 in place; flush 16KB FULLY
//     CONTIGUOUS global stores                                    [R10]
//   LDS 17952B -> 8 single-wave blocks/CU; VGPR ~220 (<256).

#define BB 16
#define TT 32768
#define FF 30
#define KK 7
#define ORD 6
#define LCH 64                  // output samples per lane
#define WARM 128
#define SPAN (64 * LCH)         // 4096 samples per block
#define NSP (TT / SPAN)         // 8 spans per (b,f) row
#define NQ ((SPAN + WARM) / 64) // 66 groups staged
#define NP4 ((SPAN + WARM) / 4) // 1056 float4 staged
#define GS4 17                  // group stride in float4 (68 floats)
#define BLK 64                  // one wave

// Transposed direct-form II step: 13 FMAs, no state shifting.
__device__ __forceinline__ float iir_step(float xv, float st[ORD],
                                          const float bcf[KK],
                                          const float acf[ORD]) {
    float y = fmaf(bcf[0], xv, st[0]);
#pragma unroll
    for (int j = 0; j < ORD - 1; ++j)
        st[j] = fmaf(-acf[j], y, fmaf(bcf[j + 1], xv, st[j + 1]));
    st[ORD - 1] = fmaf(-acf[ORD - 1], y, bcf[KK - 1] * xv);
    return y;
}

__global__ __launch_bounds__(BLK) void iir_union_kernel(
    const float* __restrict__ x,    // [B][T]
    const float* __restrict__ bs,   // [F][K]
    const float* __restrict__ as_,  // [F][K]
    float* __restrict__ out)        // [B][F][T]
{
    __shared__ __align__(16) float lx[NQ * 4 * GS4];  // 17952 B skewed tile

    const int lane = threadIdx.x;
    const int bid  = blockIdx.x;
    const int b  = bid / (FF * NSP);
    const int r  = bid % (FF * NSP);
    const int f  = r / NSP;
    const int sp = r % NSP;
    const int t0 = sp * SPAN;

    // Lane-uniform coefficients -> scalar broadcast.
    const float inv_a0 = 1.0f / as_[f * KK];
    float bcf[KK], acf[ORD];
#pragma unroll
    for (int j = 0; j < KK; ++j) bcf[j] = bs[f * KK + j] * inv_a0;
#pragma unroll
    for (int j = 0; j < ORD; ++j) acf[j] = as_[f * KK + 1 + j] * inv_a0;

    float4* __restrict__ lx4 = reinterpret_cast<float4*>(lx);
    const float* __restrict__ xrow = x + b * TT;

    // Stage x[t0-128, t0+4096): coalesced float4 loads, skewed LDS writes
    // lds4[17*(p>>4) + (p&15)]: start bank 4*(group+k) mod 32 = balanced.
    // Zero-fill t<0 (zero input keeps zero state -> exact head).
#pragma unroll
    for (int i = 0; i < (NP4 + BLK - 1) / BLK; ++i) {   // 17 (last partial)
        const int p = i * BLK + lane;
        if (p < NP4) {
            const int t = t0 - WARM + 4 * p;
            float4 v = make_float4(0.f, 0.f, 0.f, 0.f);
            if (t >= 0) v = *reinterpret_cast<const float4*>(xrow + t);
            lx4[GS4 * (p >> 4) + (p & 15)] = v;
        }
    }
    __syncthreads();   // single-wave block: cheap

    // Register-stage this lane's window: groups lane, lane+1, lane+2.
    float4 va[16], vb[16], vc[16];
#pragma unroll
    for (int k = 0; k < 16; ++k) va[k] = lx4[GS4 * lane + k];
#pragma unroll
    for (int k = 0; k < 16; ++k) vb[k] = lx4[GS4 * (lane + 1) + k];
#pragma unroll
    for (int k = 0; k < 16; ++k) vc[k] = lx4[GS4 * (lane + 2) + k];

    float st[ORD];
#pragma unroll
    for (int j = 0; j < ORD; ++j) st[j] = 0.0f;

    // Warm-up: 128 pure-register steps.
#pragma unroll
    for (int k = 0; k < 16; ++k) {
        iir_step(va[k].x, st, bcf, acf);
        iir_step(va[k].y, st, bcf, acf);
        iir_step(va[k].z, st, bcf, acf);
        iir_step(va[k].w, st, bcf, acf);
    }
#pragma unroll
    for (int k = 0; k < 16; ++k) {
        iir_step(vb[k].x, st, bcf, acf);
        iir_step(vb[k].y, st, bcf, acf);
        iir_step(vb[k].z, st, bcf, acf);
        iir_step(vb[k].w, st, bcf, acf);
    }

    // Output: 64 steps; overwrite group lane+2 in place (all lanes' reads
    // were issued above; DS ops are wave-ordered, writes can't pass them).
#pragma unroll
    for (int k = 0; k < 16; ++k) {
        float4 y;
        y.x = iir_step(vc[k].x, st, bcf, acf);
        y.y = iir_step(vc[k].y, st, bcf, acf);
        y.z = iir_step(vc[k].z, st, bcf, acf);
        y.w = iir_step(vc[k].w, st, bcf, acf);
        lx4[GS4 * (lane + 2) + k] = y;
    }
    __syncthreads();

    // Flush: 1024 float4 in t-order; every instruction = 64 lanes x 16B
    // = 1KB contiguous; whole block = 16KB sequential global stores.
    float* __restrict__ obase = out + (b * FF + f) * TT + t0;
#pragma unroll
    for (int i = 0; i < (SPAN / 4) / BLK; ++i) {        // 16
        const int p = i * BLK + lane;
        const float4 v = lx4[GS4 * ((p >> 4) + 2) + (p & 15)];
        *reinterpret_cast<float4*>(obase + 4 * p) = v;
    }
}

extern "C" void kernel_launch(void* const* d_in, const int* in_sizes, int n_in,
                              void* d_out, int out_size, void* d_ws,
                              size_t ws_size, hipStream_t stream) {
    const float* x   = (const float*)d_in[0];
    const float* bs  = (const float*)d_in[1];
    const float* as_ = (const float*)d_in[2];
    float* out = (float*)d_out;

    const int grid = BB * FF * NSP;  // 3840 single-wave blocks
    hipLaunchKernelGGL(iir_union_kernel, dim3(grid), dim3(BLK), 0, stream,
                       x, bs, as_, out);
}

// Round 15
// 27.468 us; speedup vs baseline: 1.3341x; 1.3341x over previous
//
#include <hip/hip_runtime.h>

// IIR filter bank: B=16, T=32768, F=30, order 6 (K=7).
// Overlap-and-discard chunking (CHUNK=64, WARM=128).
// R14 = R12 exactly (best: 27.9us) + two compiler-control fixes:
//   1. __launch_bounds__(64, 1): unlock >84 VGPRs (R13 counters proved
//      the 48-float4 stage never materialized: VGPR=84, reads sunk).
//   2. sched_barrier(0) after the ds_read block: forbids sinking the
//      reads into the consume loops -> all 48 issue up front, one
//      lgkmcnt drain, then 192 pure-register FMA steps per lane.
//   Keep R12's strided 512B-run flush (beat contiguous flush twice:
//   R9/R12 ~28-29us vs R10/R13 37-48us — 16KB-aligned block starts
//   appear to hotspot channels; not worth fighting).

#define BB 16
#define TT 32768
#define FF 30
#define KK 7
#define ORD 6
#define CHUNK 64
#define WARM 128
#define CPB 2                  // chunks per block
#define TSPAN (CPB * CHUNK)    // 128 samples per block
#define NBC (TT / TSPAN)       // 256 block-columns per row
#define YSTR 132               // row stride (528B, 16B-aligned)
#define XTILE (WARM + TSPAN)   // 256 floats staged x
#define BLK 64                 // ONE wave per block

// Transposed direct-form II step: 13 FMAs, no state shifting.
__device__ __forceinline__ float iir_step(float xv, float st[ORD],
                                          const float bcf[KK],
                                          const float acf[ORD]) {
    float y = fmaf(bcf[0], xv, st[0]);
#pragma unroll
    for (int j = 0; j < ORD - 1; ++j)
        st[j] = fmaf(-acf[j], y, fmaf(bcf[j + 1], xv, st[j + 1]));
    st[ORD - 1] = fmaf(-acf[ORD - 1], y, bcf[KK - 1] * xv);
    return y;
}

__global__ __launch_bounds__(BLK, 1) void iir_reg_kernel(
    const float* __restrict__ x,    // [B][T]
    const float* __restrict__ bs,   // [F][K]
    const float* __restrict__ as_,  // [F][K]
    float* __restrict__ out)        // [B][F][T]
{
    __shared__ __align__(16) float ly[FF * YSTR];   // 15840 B output tile
    __shared__ __align__(16) float lx[XTILE];       //  1024 B x tile

    const int tid = threadIdx.x;
    const int b   = blockIdx.x / NBC;
    const int bc  = blockIdx.x % NBC;
    const int bt0 = bc * TSPAN;
    const int xs  = bt0 - WARM;     // negative only for bc==0

    const int f  = tid % FF;        // lanes 0-29: cl=0, 30-59: cl=1
    const int cl = tid / FF;
    const bool active = tid < FF * CPB;

    // Lane-uniform-per-f coefficients (latency overlaps x staging below).
    float bcf[KK], acf[ORD];
    {
        const int fc = active ? f : 0;
        const float inv_a0 = 1.0f / as_[fc * KK];
#pragma unroll
        for (int j = 0; j < KK; ++j) bcf[j] = bs[fc * KK + j] * inv_a0;
#pragma unroll
        for (int j = 0; j < ORD; ++j) acf[j] = as_[fc * KK + 1 + j] * inv_a0;
    }

    // Cooperative x stage: one float4 per lane; zero-fill t<0 (zero input
    // keeps zero state -> exact head).
    {
        const float* __restrict__ xrow = x + b * TT;
        const int t = xs + 4 * tid;
        float4 v = make_float4(0.f, 0.f, 0.f, 0.f);
        if (t >= 0) v = *reinterpret_cast<const float4*>(xrow + t);
        *reinterpret_cast<float4*>(lx + 4 * tid) = v;
    }
    __syncthreads();   // single-wave block: cheap

    if (active) {
        // Register-stage the lane's whole window: 48 float4 up front.
        // Each read has only 2 distinct addresses across the wave
        // (cl groups) -> broadcast + 2-way alias = free.
        const float4* lx4 = reinterpret_cast<const float4*>(lx);
        const int g0 = 16 * cl;             // window start (float4 units)
        float4 va[16], vb[16], vc[16];
#pragma unroll
        for (int k = 0; k < 16; ++k) va[k] = lx4[g0 + k];
#pragma unroll
        for (int k = 0; k < 16; ++k) vb[k] = lx4[g0 + 16 + k];
#pragma unroll
        for (int k = 0; k < 16; ++k) vc[k] = lx4[g0 + 32 + k];
        // Nothing may cross this point: the 48 ds_reads cannot sink into
        // the consume loops below -> values stay materialized in VGPRs.
        __builtin_amdgcn_sched_barrier(0);

        float st[ORD];
#pragma unroll
        for (int j = 0; j < ORD; ++j) st[j] = 0.0f;

        // Warm-up: 128 steps from registers, zero memory stalls.
#pragma unroll
        for (int k = 0; k < 16; ++k) {
            iir_step(va[k].x, st, bcf, acf);
            iir_step(va[k].y, st, bcf, acf);
            iir_step(va[k].z, st, bcf, acf);
            iir_step(va[k].w, st, bcf, acf);
        }
#pragma unroll
        for (int k = 0; k < 16; ++k) {
            iir_step(vb[k].x, st, bcf, acf);
            iir_step(vb[k].y, st, bcf, acf);
            iir_step(vb[k].z, st, bcf, acf);
            iir_step(vb[k].w, st, bcf, acf);
        }

        // Output: 64 steps, one ds_write_b128 per 4.
        float* lyc = ly + f * YSTR + cl * CHUNK;
#pragma unroll
        for (int k = 0; k < 16; ++k) {
            float4 y;
            y.x = iir_step(vc[k].x, st, bcf, acf);
            y.y = iir_step(vc[k].y, st, bcf, acf);
            y.z = iir_step(vc[k].z, st, bcf, acf);
            y.w = iir_step(vc[k].w, st, bcf, acf);
            *reinterpret_cast<float4*>(lyc + 4 * k) = y;
        }
    }
    __syncthreads();

    // Flush: 30 rows x 128 floats = 960 float4, 15 per lane; lanes 0-31
    // cover row 2it, lanes 32-63 row 2it+1 -> two contiguous 512B runs
    // per instruction, full 64B lines only.
    float* __restrict__ obase = out + b * FF * TT + bt0;
#pragma unroll
    for (int it = 0; it < (FF * TSPAN / 4) / BLK; ++it) {  // 15
        const int j  = tid + BLK * it;
        const int fr = j >> 5;            // 32 float4 per row
        const int tl = (j & 31) << 2;
        const float4 v = *reinterpret_cast<const float4*>(ly + fr * YSTR + tl);
        *reinterpret_cast<float4*>(obase + fr * TT + tl) = v;
    }
}

extern "C" void kernel_launch(void* const* d_in, const int* in_sizes, int n_in,
                              void* d_out, int out_size, void* d_ws,
                              size_t ws_size, hipStream_t stream) {
    const float* x   = (const float*)d_in[0];
    const float* bs  = (const float*)d_in[1];
    const float* as_ = (const float*)d_in[2];
    float* out = (float*)d_out;

    const int grid = BB * NBC;  // 4096 single-wave blocks
    hipLaunchKernelGGL(iir_reg_kernel, dim3(grid), dim3(BLK), 0, stream,
                       x, bs, as_, out);
}